// Round 10
// baseline (571.413 us; speedup 1.0000x reference)
//
#include <hip/hip_runtime.h>
#include <math.h>

#define NCH 8
#define HID 20

typedef __attribute__((ext_vector_type(8))) short short8v;
typedef __attribute__((ext_vector_type(4))) float f32x4;
typedef unsigned short ushort;
typedef unsigned int uint;

// ---- workspace layout (float offsets) ----
#define OFF_F    0u            // 13*576*81   = 606528
#define OFF_BAB  606528u       // 13*576*9    = 67392
#define OFF_E    673920u       // 13*9*576*28 = 1886976  (row: E[0..24], [25]=beta)
#define OFF_I1   2560896u      // 8*64*64
#define OFF_I2   2593664u      // 8*32*32
#define OFF_XA   2601856u      // 8*8*128*128
#define OFF_XB   3650432u
#define OFF_X1A  4699008u      // 8*8*64*64
#define OFF_X1B  4961152u
#define OFF_X2A  5223296u      // 8*8*32*32
#define OFF_X2B  5288832u
#define OFF_EBH  5354368u      // 13*576*32 ushort = 119808 floats (bf16-hi E, row=(ik*8+o), k25=beta)
#define OFF_EBL  5474176u      // 13*576*32 ushort (bf16-lo residual)

#define EBLKF ((size_t)9 * 576 * 28)

__device__ __forceinline__ ushort f2bf(float x) {
  uint u = __float_as_uint(x);
  uint r = (u + 0x7fffu + ((u >> 16) & 1u)) >> 16;
  return (ushort)r;
}
__device__ __forceinline__ float bf2f(ushort h) {
  return __uint_as_float(((uint)h) << 16);
}

// K1: precomp_f (F/Bab) + img_down fused.
__global__ __launch_bounds__(256) void precomp_f_imgdown(
    const float* __restrict__ iW1, const float* __restrict__ iW2, const float* __restrict__ ib1,
    const float* __restrict__ bW1, const float* __restrict__ bW2, const float* __restrict__ bb1,
    float* __restrict__ F, float* __restrict__ Bab,
    const float* __restrict__ image, float* __restrict__ i1, float* __restrict__ i2)
{
  if (blockIdx.x >= 2370) {
    int tid = (blockIdx.x - 2370) * 256 + threadIdx.x;
    if (tid < 8 * 64 * 64) {
      int xx = tid % 64, y = (tid / 64) % 64, b = tid / 4096;
      const float* p = image + ((size_t)b * 128 + y * 2) * 128 + xx * 2;
      i1[tid] = 0.25f * (p[0] + p[1] + p[128] + p[129]);
    } else {
      int t = tid - 8 * 64 * 64;
      if (t >= 8 * 32 * 32) return;
      int xx = t % 32, y = (t / 32) % 32, b = t / 1024;
      const float* p = image + ((size_t)b * 128 + y * 4) * 128 + xx * 4;
      float s = 0.f;
      #pragma unroll
      for (int rr = 0; rr < 4; ++rr)
        #pragma unroll
        for (int cc = 0; cc < 4; ++cc) s += p[rr * 128 + cc];
      i2[t] = s * 0.0625f;
    }
    return;
  }
  int tid = blockIdx.x * 256 + threadIdx.x;
  if (tid >= 13 * 576 * 81) return;
  int ab9 = tid % 81;
  int rest = tid / 81;
  int p = rest % 576;
  int blk = rest / 576;
  if (blk == 0 && p >= 72) return;
  int ab = ab9 / 9, apbp = ab9 % 9;
  const float *W2, *W1, *b1;
  if (blk == 0) { W2 = iW2; W1 = iW1; b1 = ib1; }
  else {
    W2 = bW2 + (size_t)(blk - 1) * 576 * HID * 9;
    W1 = bW1 + (size_t)(blk - 1) * 64 * HID * 9;
    b1 = bb1 + (size_t)(blk - 1) * 64 * HID;
  }
  int g = p / 9;
  const float* w2p = W2 + (size_t)p * HID * 9 + ab;
  const float* w1p = W1 + (size_t)g * HID * 9 + apbp;
  float s = 0.f;
  #pragma unroll
  for (int cc = 0; cc < HID; ++cc) s = fmaf(w2p[cc * 9], w1p[cc * 9], s);
  F[(size_t)(blk * 576 + p) * 81 + ab9] = s;
  if (apbp == 0) {
    const float* b1p = b1 + g * HID;
    float sb = 0.f;
    #pragma unroll
    for (int cc = 0; cc < HID; ++cc) sb = fmaf(w2p[cc * 9], b1p[cc], sb);
    Bab[(size_t)(blk * 576 + p) * 9 + ab] = sb;
  }
}

// K2: E-class tables (fp32, for edge/corner paths).
__global__ __launch_bounds__(256) void precomp_e(
    const float* __restrict__ F, const float* __restrict__ Bab,
    const float* __restrict__ ib2, const float* __restrict__ bb2,
    float* __restrict__ E)
{
  int tid = blockIdx.x * 256 + threadIdx.x;
  if (tid >= 13 * 9 * 576 * 25) return;
  int uv = tid % 25;
  int rest = tid / 25;
  int p = rest % 576;
  int rest2 = rest / 576;
  int cls = rest2 % 9;
  int blk = rest2 / 9;
  if (blk == 0 && p >= 72) return;
  int yc = cls / 3, xc = cls % 3;
  int alo = (yc == 0) ? 1 : 0, ahi = (yc == 2) ? 1 : 2;
  int blo = (xc == 0) ? 1 : 0, bhi = (xc == 2) ? 1 : 2;
  int u = uv / 5, v = uv % 5;
  const float* Fp = F + (size_t)(blk * 576 + p) * 81;
  float s = 0.f;
  for (int a = alo; a <= ahi; ++a) {
    int a2 = u - a;
    if (a2 < 0 || a2 > 2) continue;
    for (int bq = blo; bq <= bhi; ++bq) {
      int b2i = v - bq;
      if (b2i < 0 || b2i > 2) continue;
      s += Fp[(a * 3 + bq) * 9 + a2 * 3 + b2i];
    }
  }
  float* Ep = E + (size_t)((blk * 9 + cls) * 576 + p) * 28;
  Ep[uv] = s;
  if (uv == 0) {
    float beta = (blk == 0) ? ib2[p] : bb2[(size_t)(blk - 1) * 576 + p];
    const float* Bp = Bab + (size_t)(blk * 576 + p) * 9;
    for (int a = alo; a <= ahi; ++a)
      for (int bq = blo; bq <= bhi; ++bq)
        beta += Bp[a * 3 + bq];
    Ep[25] = beta;
  }
}

// K3: pack interior-class E into bf16 hi/lo tables, row = ik*8+o, k=0..24 coeffs,
// k=25 beta, k>=26 zero. blk0 (nci=1): 72 real rows, rest zero.
__global__ __launch_bounds__(256) void epack(
    const float* __restrict__ E, ushort* __restrict__ Ebh, ushort* __restrict__ Ebl)
{
  int tid = blockIdx.x * 256 + threadIdx.x;
  if (tid >= 13 * 576 * 32) return;
  int k = tid & 31;
  int row = (tid >> 5) % 576;
  int blk = tid / (576 * 32);
  ushort hi = 0, lo = 0;
  int nci = (blk == 0) ? 1 : 8;
  int rows_real = nci * 72;  // nci*9*8
  if (row < rows_real && k < 26) {
    int ik = row >> 3, o = row & 7;
    int i = ik / 9, k9 = ik % 9;
    int p = (o * nci + i) * 9 + k9;
    const float* src = E + ((size_t)(blk * 9 + 4) * 576 + p) * 28;
    float val = (k < 25) ? src[k] : src[25];
    hi = f2bf(val);
    lo = f2bf(val - bf2f(hi));
  }
  Ebh[tid] = hi;
  Ebl[tid] = lo;
}

__global__ __launch_bounds__(256) void x_down(
    const float* __restrict__ x, float* __restrict__ x1, float* __restrict__ x2)
{
  int tid = blockIdx.x * 256 + threadIdx.x;
  if (tid < 8 * NCH * 64 * 64) {
    int xx = tid % 64, y = (tid / 64) % 64, rest = tid / 4096;
    const float* p = x + ((size_t)rest * 128 + y * 2) * 128 + xx * 2;
    x1[tid] = 0.25f * (p[0] + p[1] + p[128] + p[129]);
  } else {
    int t = tid - 8 * NCH * 64 * 64;
    if (t >= 8 * NCH * 32 * 32) return;
    int xx = t % 32, y = (t / 32) % 32, rest = t / 1024;
    const float* p = x + ((size_t)rest * 128 + y * 4) * 128 + xx * 4;
    float s = 0.f;
    #pragma unroll
    for (int rr = 0; rr < 4; ++rr)
      #pragma unroll
      for (int cc = 0; cc < 4; ++cc) s += p[rr * 128 + cc];
    x2[t] = s * 0.0625f;
  }
}

// Unified per-step kernel, 512 threads/block.
// Interior = MFMA path: 16x16 px tile, 8 waves x 2 pixel rows each.
// Per mt: one E-fragment pair feeds 6 MFMAs (2 row-groups x hi/lo split, indep chains);
// E prefetched one mt ahead. Edge/corner paths use waves 0-3 only.
__global__ __launch_bounds__(512, 2) void sm_step(
    const float* __restrict__ xi0, float* __restrict__ xo0, const float* __restrict__ im0, const ushort* __restrict__ Eh0, const ushort* __restrict__ El0, const float* __restrict__ Ee0, int N0, int nci0,
    const float* __restrict__ xi1, float* __restrict__ xo1, const float* __restrict__ im1, const ushort* __restrict__ Eh1, const ushort* __restrict__ El1, const float* __restrict__ Ee1, int N1, int nci1,
    const float* __restrict__ xi2, float* __restrict__ xo2, const float* __restrict__ im2, const ushort* __restrict__ Eh2, const ushort* __restrict__ El2, const float* __restrict__ Ee2, int N2, int nci2,
    int i0, int i01, int i012, int e0e, int e01e, int e012e)
{
  __shared__ float xsl[NCH][18][18];   // x tile 16x16 + halo 1
  __shared__ float isl[20][20];        // img tile + halo 2

  int bid = blockIdx.x;
  int tid = threadIdx.x;
  const float* __restrict__ xin;
  float* __restrict__ xout;
  const float* __restrict__ img;
  int N, nci;

  if (bid < i012) {
    // ---------------- interior (MFMA) ----------------
    const ushort* __restrict__ EH;
    const ushort* __restrict__ EL;
    int lb, s;
    if (bid < i0)       { s = 0; lb = bid; }
    else if (bid < i01) { s = 1; lb = bid - i0; }
    else                { s = 2; lb = bid - i01; }
    if (s == 0)      { xin = xi0; xout = xo0; img = im0; EH = Eh0; EL = El0; N = N0; nci = nci0; }
    else if (s == 1) { xin = xi1; xout = xo1; img = im1; EH = Eh1; EL = El1; N = N1; nci = nci1; }
    else             { xin = xi2; xout = xo2; img = im2; EH = Eh2; EL = El2; N = N2; nci = nci2; }

    int tilesx = N >> 4;
    int tiles = tilesx * tilesx;
    int b = lb / tiles;
    int trem = lb % tiles;
    int ty = trem / tilesx, tx = trem % tilesx;
    int X0 = tx * 16, Y0 = ty * 16;

    // stage img tile (+2 halo) and x tile (+1 halo)
    const float* imgb = img + (size_t)b * N * N;
    for (int idx = tid; idx < 400; idx += 512) {
      int r = idx / 20, c = idx % 20;
      int gy = Y0 - 2 + r, gx = X0 - 2 + c;
      float v = 0.f;
      if (gy >= 0 && gy < N && gx >= 0 && gx < N) v = imgb[gy * N + gx];
      isl[r][c] = v;
    }
    const float* xinb = xin + (size_t)b * nci * N * N;
    for (int idx = tid; idx < nci * 324; idx += 512) {
      int i = idx / 324;
      int rem = idx - i * 324;
      int r = rem / 18, c = rem % 18;
      int gy = Y0 - 1 + r, gx = X0 - 1 + c;
      float v = 0.f;
      if (gy >= 0 && gy < N && gx >= 0 && gx < N) v = xinb[(size_t)i * N * N + gy * N + gx];
      xsl[i][r][c] = v;
    }
    __syncthreads();

    int l = tid & 63;
    int wid = tid >> 6;          // 0..7, wave owns pixel rows 2*wid, 2*wid+1
    int c15 = l & 15;
    int kb = ((l >> 4) & 3) * 8;
    int hi5 = l >> 5;
    const int T = (nci == 1) ? 5 : 36;
    const int nikr = nci * 9;
    const int pyl0 = wid * 2, pyl1 = pyl0 + 1;

    // build B fragments (patch, bf16 hi/lo) for both rows; k=25 -> 1.0, k>25 -> 0
    short8v Ph0, Pl0, Ph1, Pl1;
    #pragma unroll
    for (int j = 0; j < 8; ++j) {
      int k = kb + j;
      int u = (k * 13) >> 6;
      int uc = u > 4 ? 4 : u;
      int v = k - 5 * uc;
      int vc = v > 4 ? 4 : (v < 0 ? 0 : v);
      float pv0 = isl[pyl0 + uc][c15 + vc];
      float pv1 = isl[pyl1 + uc][c15 + vc];
      pv0 = (k < 25) ? pv0 : ((k == 25) ? 1.f : 0.f);
      pv1 = (k < 25) ? pv1 : ((k == 25) ? 1.f : 0.f);
      ushort h0 = f2bf(pv0), h1 = f2bf(pv1);
      Ph0[j] = (short)h0; Pl0[j] = (short)f2bf(pv0 - bf2f(h0));
      Ph1[j] = (short)h1; Pl1[j] = (short)f2bf(pv1 - bf2f(h1));
    }

    f32x4 aco0 = {0.f, 0.f, 0.f, 0.f};
    f32x4 aco1 = {0.f, 0.f, 0.f, 0.f};

    const ushort* __restrict__ ehp = EH + (size_t)c15 * 32 + kb;
    const ushort* __restrict__ elp = EL + (size_t)c15 * 32 + kb;
    short8v Ah = *(const short8v*)(ehp);
    short8v Al = *(const short8v*)(elp);

    #pragma unroll 2
    for (int mt = 0; mt < T; ++mt) {
      short8v AhN, AlN;
      if (mt + 1 < T) {
        AhN = *(const short8v*)(ehp + (size_t)(mt + 1) * 16 * 32);
        AlN = *(const short8v*)(elp + (size_t)(mt + 1) * 16 * 32);
      }
      int ik = 2 * mt + hi5;
      float xp0 = 0.f, xp1 = 0.f;
      if (ik < nikr) {
        int i = (ik * 57) >> 9;          // /9 for 0..71
        int k9 = ik - 9 * i;
        int dy = (k9 * 11) >> 5;         // /3 for 0..8
        int dx = k9 - 3 * dy;
        xp0 = xsl[i][pyl0 + dy][c15 + dx];
        xp1 = xsl[i][pyl1 + dy][c15 + dx];
      }
      f32x4 z = {0.f, 0.f, 0.f, 0.f};
      f32x4 d1 = __builtin_amdgcn_mfma_f32_16x16x32_bf16(Ah, Ph0, z, 0, 0, 0);
      f32x4 d2 = __builtin_amdgcn_mfma_f32_16x16x32_bf16(Al, Ph0, z, 0, 0, 0);
      d2 = __builtin_amdgcn_mfma_f32_16x16x32_bf16(Ah, Pl0, d2, 0, 0, 0);
      f32x4 e1 = __builtin_amdgcn_mfma_f32_16x16x32_bf16(Ah, Ph1, z, 0, 0, 0);
      f32x4 e2 = __builtin_amdgcn_mfma_f32_16x16x32_bf16(Al, Ph1, z, 0, 0, 0);
      e2 = __builtin_amdgcn_mfma_f32_16x16x32_bf16(Ah, Pl1, e2, 0, 0, 0);
      #pragma unroll
      for (int j = 0; j < 4; ++j) {
        aco0[j] = fmaf(d1[j] + d2[j], xp0, aco0[j]);
        aco1[j] = fmaf(e1[j] + e2[j], xp1, aco1[j]);
      }
      Ah = AhN; Al = AlN;
    }

    // combine ik parities (lane ^ 32 has same o-quad & pixel)
    #pragma unroll
    for (int j = 0; j < 4; ++j) {
      aco0[j] += __shfl_xor(aco0[j], 32, 64);
      aco1[j] += __shfl_xor(aco1[j], 32, 64);
    }

    if (l < 32) {
      int ob = ((l >> 4) & 1) * 4;
      int px = X0 + c15;
      float* yb = xout + (size_t)b * NCH * N * N;
      if (px >= 1 && px <= N - 2) {
        int py0 = Y0 + pyl0, py1 = Y0 + pyl1;
        if (py0 >= 1 && py0 <= N - 2) {
          #pragma unroll
          for (int j = 0; j < 4; ++j) {
            float v = aco0[j];
            v = v > 0.f ? v : expm1f(v);
            yb[(size_t)(ob + j) * N * N + py0 * N + px] = v;
          }
        }
        if (py1 >= 1 && py1 <= N - 2) {
          #pragma unroll
          for (int j = 0; j < 4; ++j) {
            float v = aco1[j];
            v = v > 0.f ? v : expm1f(v);
            yb[(size_t)(ob + j) * N * N + py1 * N + px] = v;
          }
        }
      }
    }
    return;
  }

  if (bid < e012e) {
    // ---------------- edges (excl corners), VALU path, waves 0-3 only ----------------
    if (tid >= 256) return;
    const float* __restrict__ E;
    int eb = bid - i012;
    int lb, s;
    if (eb < e0e - i012)        { s = 0; lb = eb; }
    else if (eb < e01e - i012)  { s = 1; lb = eb - (e0e - i012); }
    else                        { s = 2; lb = eb - (e01e - i012); }
    if (s == 0)      { xin = xi0; xout = xo0; img = im0; E = Ee0; N = N0; nci = nci0; }
    else if (s == 1) { xin = xi1; xout = xo1; img = im1; E = Ee1; N = N1; nci = nci1; }
    else             { xin = xi2; xout = xo2; img = im2; E = Ee2; N = N2; nci = nci2; }

    int H = (N - 2 + 63) / 64;
    int half = lb % H;
    int b = (lb / H) % 8;
    int side = lb / (H * 8);

    int lane = tid & 63;
    int orow = tid >> 6;   // 0..3 (wave-uniform)
    int pos = 1 + half * 64 + lane;
    bool act = pos < N - 1;
    if (!act) pos = 1;

    int y, x, cls;
    if (side == 0)      { y = 0;     x = pos;  cls = 1; }
    else if (side == 1) { y = N - 1; x = pos;  cls = 7; }
    else if (side == 2) { x = 0;     y = pos;  cls = 3; }
    else                { x = N - 1; y = pos;  cls = 5; }

    const float* __restrict__ Ec = E + (size_t)cls * 576 * 28;
    const float* imb = img + (size_t)b * N * N;
    float P[25];
    #pragma unroll
    for (int u = 0; u < 5; ++u)
      #pragma unroll
      for (int v = 0; v < 5; ++v) {
        int gy = y + u - 2, gx = x + v - 2;
        P[u * 5 + v] = (gy >= 0 && gy < N && gx >= 0 && gx < N) ? imb[gy * N + gx] : 0.f;
      }

    const float* xb = xin + (size_t)b * nci * N * N;
    float acc0 = 0.f, acc1 = 0.f;
    const int oA = orow, oB = orow + 4;
    for (int i = 0; i < nci; ++i) {
      #pragma unroll 1
      for (int k9 = 0; k9 < 9; ++k9) {
        int yy = y + k9 / 3 - 1, xx = x + k9 % 3 - 1;
        float xv = (yy >= 0 && yy < N && xx >= 0 && xx < N) ? xb[(size_t)i * N * N + yy * N + xx] : 0.f;
        const float* __restrict__ e0 = Ec + (size_t)((oA * nci + i) * 9 + k9) * 28;
        const float* __restrict__ e1 = Ec + (size_t)((oB * nci + i) * 9 + k9) * 28;
        float kv0 = e0[25], kv1 = e1[25];
        #pragma unroll
        for (int uv = 0; uv < 25; ++uv) {
          kv0 = fmaf(e0[uv], P[uv], kv0);
          kv1 = fmaf(e1[uv], P[uv], kv1);
        }
        acc0 = fmaf(kv0, xv, acc0);
        acc1 = fmaf(kv1, xv, acc1);
      }
    }
    if (act) {
      float v0 = acc0 > 0.f ? acc0 : expm1f(acc0);
      float v1 = acc1 > 0.f ? acc1 : expm1f(acc1);
      xout[(((size_t)b * NCH + oA) * N + y) * N + x] = v0;
      xout[(((size_t)b * NCH + oB) * N + y) * N + x] = v1;
    }
    return;
  }

  // ---------------- corners, waves 0-3 only ----------------
  {
    if (tid >= 256) return;
    const float* __restrict__ E;
    int s = bid - e012e;
    if (s == 0)      { xin = xi0; xout = xo0; img = im0; E = Ee0; N = N0; nci = nci0; }
    else if (s == 1) { xin = xi1; xout = xo1; img = im1; E = Ee1; N = N1; nci = nci1; }
    else             { xin = xi2; xout = xo2; img = im2; E = Ee2; N = N2; nci = nci2; }

    int corner = tid >> 6;  // 0..3
    int lane = tid & 63;
    int y = (corner & 2) ? N - 1 : 0;
    int x = (corner & 1) ? N - 1 : 0;
    int cls = ((corner & 2) ? 6 : 0) + ((corner & 1) ? 2 : 0);
    int b = lane >> 3;
    int o = lane & 7;

    const float* __restrict__ Ec = E + (size_t)cls * 576 * 28;
    const float* imb = img + (size_t)b * N * N;
    float P[25];
    #pragma unroll
    for (int u = 0; u < 5; ++u)
      #pragma unroll
      for (int v = 0; v < 5; ++v) {
        int gy = y + u - 2, gx = x + v - 2;
        P[u * 5 + v] = (gy >= 0 && gy < N && gx >= 0 && gx < N) ? imb[gy * N + gx] : 0.f;
      }
    const float* xb = xin + (size_t)b * nci * N * N;
    float acc = 0.f;
    for (int i = 0; i < nci; ++i) {
      #pragma unroll 1
      for (int k9 = 0; k9 < 9; ++k9) {
        int yy = y + k9 / 3 - 1, xx = x + k9 % 3 - 1;
        float xv = (yy >= 0 && yy < N && xx >= 0 && xx < N) ? xb[(size_t)i * N * N + yy * N + xx] : 0.f;
        const float* e = Ec + (size_t)((o * nci + i) * 9 + k9) * 28;
        float kv = e[25];
        #pragma unroll
        for (int uv = 0; uv < 25; ++uv) kv = fmaf(e[uv], P[uv], kv);
        acc = fmaf(kv, xv, acc);
      }
    }
    float v0 = acc > 0.f ? acc : expm1f(acc);
    xout[(((size_t)b * NCH + o) * N + y) * N + x] = v0;
  }
}

__global__ __launch_bounds__(256) void final_merge(
    const float* __restrict__ x, const float* __restrict__ x1, const float* __restrict__ x2,
    const float* __restrict__ w5, const float* __restrict__ b5,
    const float* __restrict__ w6, const float* __restrict__ b6,
    float* __restrict__ out)
{
  int tid = blockIdx.x * 256 + threadIdx.x;
  if (tid >= 8 * 128 * 128) return;
  int xx = tid % 128, y = (tid / 128) % 128, b = tid / 16384;
  float v[NCH];
  #pragma unroll
  for (int i = 0; i < NCH; ++i) {
    v[i] = x[((size_t)(b * NCH + i) * 128 + y) * 128 + xx]
         + x1[((size_t)(b * NCH + i) * 64 + (y >> 1)) * 64 + (xx >> 1)]
         + x2[((size_t)(b * NCH + i) * 32 + (y >> 2)) * 32 + (xx >> 2)];
  }
  float o6 = b6[0];
  #pragma unroll
  for (int o = 0; o < NCH; ++o) {
    float h = b5[o];
    #pragma unroll
    for (int i = 0; i < NCH; ++i) h = fmaf(w5[o * NCH + i], v[i], h);
    h = h > 0.f ? h : expm1f(h);
    o6 = fmaf(w6[o], h, o6);
  }
  out[tid] = o6;
}

extern "C" void kernel_launch(void* const* d_in, const int* in_sizes, int n_in,
                              void* d_out, int out_size, void* d_ws, size_t ws_size,
                              hipStream_t stream) {
  const float* image = (const float*)d_in[0];
  const float* x_in  = (const float*)d_in[1];
  const float* iW1   = (const float*)d_in[2];
  const float* ib1   = (const float*)d_in[3];
  const float* iW2   = (const float*)d_in[4];
  const float* ib2   = (const float*)d_in[5];
  const float* bW1   = (const float*)d_in[6];
  const float* bb1   = (const float*)d_in[7];
  const float* bW2   = (const float*)d_in[8];
  const float* bb2   = (const float*)d_in[9];
  const float* w5    = (const float*)d_in[10];
  const float* b5    = (const float*)d_in[11];
  const float* w6    = (const float*)d_in[12];
  const float* b6    = (const float*)d_in[13];
  float* ws = (float*)d_ws;

  float* F    = ws + OFF_F;
  float* Bab  = ws + OFF_BAB;
  float* E    = ws + OFF_E;
  float* i1   = ws + OFF_I1;
  float* i2   = ws + OFF_I2;
  float* xA   = ws + OFF_XA;
  float* xB   = ws + OFF_XB;
  float* x1A  = ws + OFF_X1A;
  float* x1B  = ws + OFF_X1B;
  float* x2A  = ws + OFF_X2A;
  float* x2B  = ws + OFF_X2B;
  ushort* Ebh = (ushort*)(ws + OFF_EBH);
  ushort* Ebl = (ushort*)(ws + OFF_EBL);

  precomp_f_imgdown<<<2530, 256, 0, stream>>>(iW1, iW2, ib1, bW1, bW2, bb1, F, Bab, image, i1, i2);
  precomp_e<<<6582, 256, 0, stream>>>(F, Bab, ib2, bb2, E);
  epack<<<936, 256, 0, stream>>>(E, Ebh, Ebl);

  const size_t EPB = (size_t)576 * 32;

  // ---- init (blk 0, nc_in=1, scale0 only) ----
  // interior: 8b * 64 tiles(16x16) = 512; edges 4*8*2 = 64; corner 1 -> 577
  sm_step<<<577, 512, 0, stream>>>(
      x_in, xA, image, Ebh, Ebl, E, 128, 1,
      x_in, xA, image, Ebh, Ebl, E, 128, 1,
      x_in, xA, image, Ebh, Ebl, E, 128, 1,
      512, 512, 512, 576, 576, 576);
  x_down<<<1280, 256, 0, stream>>>(xA, x1A, x2A);

  float* xr = xA; float* xw = xB;
  float* x1r = x1A; float* x1w = x1B;
  float* x2r = x2A; float* x2w = x2B;
  for (int t = 0; t < 4; ++t) {
    int b0 = 1 + 3 * t, b1 = 2 + 3 * t, b2 = 3 + 3 * t;
    // interior: 512 + 128 + 32 = 672; edges: 64 + 32 + 32 = 128; corners: 3 -> 803
    sm_step<<<803, 512, 0, stream>>>(
        xr, xw, image, Ebh + b0 * EPB, Ebl + b0 * EPB, E + b0 * EBLKF, 128, 8,
        x1r, x1w, i1,  Ebh + b1 * EPB, Ebl + b1 * EPB, E + b1 * EBLKF, 64, 8,
        x2r, x2w, i2,  Ebh + b2 * EPB, Ebl + b2 * EPB, E + b2 * EBLKF, 32, 8,
        512, 640, 672, 736, 768, 800);
    float* tmp;
    tmp = xr; xr = xw; xw = tmp;
    tmp = x1r; x1r = x1w; x1w = tmp;
    tmp = x2r; x2r = x2w; x2w = tmp;
  }
  final_merge<<<512, 256, 0, stream>>>(xr, x1r, x2r, w5, b5, w6, b6, (float*)d_out);
}